// Round 2
// baseline (591.652 us; speedup 1.0000x reference)
//
#include <hip/hip_runtime.h>
#include <hip/hip_bf16.h>
#include <stdint.h>

#define HH 768
#define WW 768
#define NN 200000
#define CI 256
#define CB 64

typedef __attribute__((ext_vector_type(8))) __bf16 bf16x8;
typedef __attribute__((ext_vector_type(4))) float f32x4;

__device__ inline unsigned short f2bf(float f) {
    union { float f; unsigned int i; } v; v.f = f;
    unsigned int r = v.i + 0x7FFF + ((v.i >> 16) & 1);
    return (unsigned short)(r >> 16);
}
__device__ inline f32x4 mfma16(bf16x8 a, bf16x8 b, f32x4 c) {
    return __builtin_amdgcn_mfma_f32_16x16x32_bf16(a, b, c, 0, 0, 0);
}
__device__ inline bf16x8 ldfrag(const unsigned short* p) {
    return *(const bf16x8*)p;
}
// load 8 consecutive f32 and convert to a bf16x8 fragment
__device__ inline bf16x8 ldfrag_f32(const float* p) {
    float4 f0 = *(const float4*)(p);
    float4 f1 = *(const float4*)(p + 4);
    bf16x8 a;
    a[0] = (__bf16)f0.x; a[1] = (__bf16)f0.y; a[2] = (__bf16)f0.z; a[3] = (__bf16)f0.w;
    a[4] = (__bf16)f1.x; a[5] = (__bf16)f1.y; a[6] = (__bf16)f1.z; a[7] = (__bf16)f1.w;
    return a;
}

// ---------------- prep kernels ----------------

__global__ void k_scatter(const int* __restrict__ coords, int* __restrict__ idx_map) {
    int i = blockIdx.x * 256 + threadIdx.x;
    if (i < NN) idx_map[coords[i]] = i;
}

// transpose weights to n-major (B-fragment friendly: row n, contiguous k), f32 -> bf16
__global__ void k_prepw(const float* __restrict__ w1,
                        const float* __restrict__ w2,
                        const float* __restrict__ w3,
                        unsigned short* __restrict__ w1t,
                        unsigned short* __restrict__ w2t,
                        unsigned short* __restrict__ w3t) {
    int tid = blockIdx.x * 256 + threadIdx.x;
    int stride = gridDim.x * 256;
    for (int i = tid; i < CI * CB; i += stride) {      // w1 [256][64] -> w1t [64][256]
        int k = i / CB, n = i % CB;
        w1t[n * CI + k] = f2bf(w1[i]);
    }
    for (int i = tid; i < 9 * CB * CB; i += stride) {  // w2 [9][64][64] -> per-tap [n][k]
        int t = i / (CB * CB), rem = i % (CB * CB);
        int k = rem / CB, n = rem % CB;
        w2t[t * CB * CB + n * CB + k] = f2bf(w2[i]);
    }
    for (int i = tid; i < CB * CI; i += stride) {      // w3 [64][256] -> w3t [256][64]
        int k = i / CI, n = i % CI;
        w3t[n * CB + k] = f2bf(w3[i]);
    }
}

// ---------------- stage 1: out1 = relu((feats @ w1)*s1 + b1), N x 64 (bf16 out) ----------------

__global__ __launch_bounds__(256) void k_gemm1(const float* __restrict__ feats,
                                               const unsigned short* __restrict__ w1t,
                                               const float* __restrict__ s1,
                                               const float* __restrict__ b1,
                                               unsigned short* __restrict__ out1) {
    const int wave = threadIdx.x >> 6;
    const int lane = threadIdx.x & 63;
    const int m = lane & 15;
    const int quad = lane >> 4;
    const int row0 = blockIdx.x * 64 + wave * 16;
    const int row = row0 + m;

    f32x4 acc[4];
#pragma unroll
    for (int t = 0; t < 4; ++t) acc[t] = (f32x4){0.f, 0.f, 0.f, 0.f};

    const float* arow = feats + row * CI + quad * 8;
#pragma unroll
    for (int ks = 0; ks < CI / 32; ++ks) {
        bf16x8 a = ldfrag_f32(arow + ks * 32);
#pragma unroll
        for (int t = 0; t < 4; ++t) {
            bf16x8 b = ldfrag(w1t + (t * 16 + m) * CI + quad * 8 + ks * 32);
            acc[t] = mfma16(a, b, acc[t]);
        }
    }

#pragma unroll
    for (int t = 0; t < 4; ++t) {
        int col = t * 16 + m;
        float sc = s1[col], bi = b1[col];
#pragma unroll
        for (int r = 0; r < 4; ++r) {
            int orow = row0 + quad * 4 + r;
            float v = acc[t][r] * sc + bi;
            v = v > 0.f ? v : 0.f;
            out1[orow * CB + col] = f2bf(v);
        }
    }
}

// ---------------- stage 2: gathered 3x3 conv + bn2 + relu, N x 64 (bf16 in/out) ----------------

__global__ __launch_bounds__(256) void k_conv(const unsigned short* __restrict__ out1,
                                              const unsigned short* __restrict__ w2t,
                                              const int* __restrict__ coords,
                                              const int* __restrict__ idx_map,
                                              const float* __restrict__ s2,
                                              const float* __restrict__ b2,
                                              unsigned short* __restrict__ out2) {
    const int wave = threadIdx.x >> 6;
    const int lane = threadIdx.x & 63;
    const int m = lane & 15;
    const int quad = lane >> 4;
    const int row0 = blockIdx.x * 64 + wave * 16;
    const int row = row0 + m;

    const int c = coords[row];
    const int y = c / WW, x = c - y * WW;

    f32x4 acc[4];
#pragma unroll
    for (int t = 0; t < 4; ++t) acc[t] = (f32x4){0.f, 0.f, 0.f, 0.f};

#pragma unroll
    for (int t = 0; t < 9; ++t) {
        const int dy = t / 3 - 1, dx = t % 3 - 1;
        const int ny = y + dy, nx = x + dx;
        int r = -1;
        if (ny >= 0 && ny < HH && nx >= 0 && nx < WW) r = idx_map[ny * WW + nx];
#pragma unroll
        for (int ks = 0; ks < 2; ++ks) {
            bf16x8 a;
#pragma unroll
            for (int j = 0; j < 8; ++j) a[j] = (__bf16)0.0f;
            if (r >= 0) a = ldfrag(out1 + r * CB + quad * 8 + ks * 32);
#pragma unroll
            for (int nt = 0; nt < 4; ++nt) {
                bf16x8 b = ldfrag(w2t + t * CB * CB + (nt * 16 + m) * CB + quad * 8 + ks * 32);
                acc[nt] = mfma16(a, b, acc[nt]);
            }
        }
    }

#pragma unroll
    for (int nt = 0; nt < 4; ++nt) {
        int col = nt * 16 + m;
        float sc = s2[col], bi = b2[col];
#pragma unroll
        for (int r = 0; r < 4; ++r) {
            int orow = row0 + quad * 4 + r;
            float v = acc[nt][r] * sc + bi;
            v = v > 0.f ? v : 0.f;
            out2[orow * CB + col] = f2bf(v);
        }
    }
}

// ---------------- stage 3: out = relu((out2 @ w3)*s3 + b3 + feats), N x 256 (f32 out) ----------------

__global__ __launch_bounds__(256) void k_gemm3(const unsigned short* __restrict__ out2,
                                               const unsigned short* __restrict__ w3t,
                                               const float* __restrict__ s3,
                                               const float* __restrict__ b3,
                                               const float* __restrict__ feats,
                                               float* __restrict__ out) {
    const int wave = threadIdx.x >> 6;
    const int lane = threadIdx.x & 63;
    const int m = lane & 15;
    const int quad = lane >> 4;
    const int row0 = blockIdx.x * 64 + wave * 16;
    const int row = row0 + m;

    f32x4 acc[16];
#pragma unroll
    for (int t = 0; t < 16; ++t) acc[t] = (f32x4){0.f, 0.f, 0.f, 0.f};

    bf16x8 a0 = ldfrag(out2 + row * CB + quad * 8);
    bf16x8 a1 = ldfrag(out2 + row * CB + quad * 8 + 32);
#pragma unroll
    for (int nt = 0; nt < 16; ++nt) {
        const unsigned short* bp = w3t + (nt * 16 + m) * CB + quad * 8;
        acc[nt] = mfma16(a0, ldfrag(bp), acc[nt]);
        acc[nt] = mfma16(a1, ldfrag(bp + 32), acc[nt]);
    }

#pragma unroll
    for (int nt = 0; nt < 16; ++nt) {
        int col = nt * 16 + m;
        float sc = s3[col], bi = b3[col];
#pragma unroll
        for (int r = 0; r < 4; ++r) {
            int orow = row0 + quad * 4 + r;
            float v = acc[nt][r] * sc + bi + feats[orow * CI + col];
            v = v > 0.f ? v : 0.f;
            out[orow * CI + col] = v;
        }
    }
}

// ---------------- launch ----------------

extern "C" void kernel_launch(void* const* d_in, const int* in_sizes, int n_in,
                              void* d_out, int out_size, void* d_ws, size_t ws_size,
                              hipStream_t stream) {
    const float* feats = (const float*)d_in[0];
    const int* coords = (const int*)d_in[1];
    const float* w1 = (const float*)d_in[2];
    const float* w2 = (const float*)d_in[3];
    const float* w3 = (const float*)d_in[4];
    const float* s1 = (const float*)d_in[5];
    const float* b1 = (const float*)d_in[6];
    const float* s2 = (const float*)d_in[7];
    const float* b2 = (const float*)d_in[8];
    const float* s3 = (const float*)d_in[9];
    const float* b3 = (const float*)d_in[10];
    float* out = (float*)d_out;

    char* ws = (char*)d_ws;
    // workspace layout (all 16B-aligned):
    int* idx_map        = (int*)(ws + 0);                       // 768*768*4    = 2,359,296
    unsigned short* w1t = (unsigned short*)(ws + 2359296);      // 64*256*2     = 32,768
    unsigned short* w2t = (unsigned short*)(ws + 2392064);      // 9*64*64*2    = 73,728
    unsigned short* w3t = (unsigned short*)(ws + 2465792);      // 256*64*2     = 32,768
    unsigned short* out1= (unsigned short*)(ws + 2498560);      // 200000*64*2  = 25,600,000
    unsigned short* out2= (unsigned short*)(ws + 28098560);     // 200000*64*2  = 25,600,000
    // total: 53,698,560 bytes

    hipMemsetAsync(idx_map, 0xFF, (size_t)HH * WW * 4, stream);
    k_scatter<<<(NN + 255) / 256, 256, 0, stream>>>(coords, idx_map);
    k_prepw<<<64, 256, 0, stream>>>(w1, w2, w3, w1t, w2t, w3t);
    k_gemm1<<<NN / 64, 256, 0, stream>>>(feats, w1t, s1, b1, out1);
    k_conv<<<NN / 64, 256, 0, stream>>>(out1, w2t, coords, idx_map, s2, b2, out2);
    k_gemm3<<<NN / 64, 256, 0, stream>>>(out2, w3t, s3, b3, feats, out);
}

// Round 3
// 526.603 us; speedup vs baseline: 1.1235x; 1.1235x over previous
//
#include <hip/hip_runtime.h>
#include <hip/hip_bf16.h>
#include <stdint.h>

#define HH 768
#define WW 768
#define NN 200000
#define CI 256
#define CB 64

typedef __attribute__((ext_vector_type(8))) __bf16 bf16x8;
typedef __attribute__((ext_vector_type(4))) float f32x4;

__device__ inline unsigned short f2bf(float f) {
    union { float f; unsigned int i; } v; v.f = f;
    unsigned int r = v.i + 0x7FFF + ((v.i >> 16) & 1);
    return (unsigned short)(r >> 16);
}
__device__ inline f32x4 mfma16(bf16x8 a, bf16x8 b, f32x4 c) {
    return __builtin_amdgcn_mfma_f32_16x16x32_bf16(a, b, c, 0, 0, 0);
}
__device__ inline bf16x8 ldfrag(const unsigned short* p) {
    return *(const bf16x8*)p;
}
__device__ inline bf16x8 ldfrag_f32(const float* p) {
    float4 f0 = *(const float4*)(p);
    float4 f1 = *(const float4*)(p + 4);
    bf16x8 a;
    a[0] = (__bf16)f0.x; a[1] = (__bf16)f0.y; a[2] = (__bf16)f0.z; a[3] = (__bf16)f0.w;
    a[4] = (__bf16)f1.x; a[5] = (__bf16)f1.y; a[6] = (__bf16)f1.z; a[7] = (__bf16)f1.w;
    return a;
}

// ---------------- prep kernels ----------------

__global__ void k_scatter(const int* __restrict__ coords, int* __restrict__ idx_map) {
    int i = blockIdx.x * 256 + threadIdx.x;
    if (i < NN) idx_map[coords[i]] = i;
}

__global__ void k_prepw(const float* __restrict__ w1,
                        const float* __restrict__ w2,
                        const float* __restrict__ w3,
                        unsigned short* __restrict__ w1t,
                        unsigned short* __restrict__ w2t,
                        unsigned short* __restrict__ w3t) {
    int tid = blockIdx.x * 256 + threadIdx.x;
    int stride = gridDim.x * 256;
    for (int i = tid; i < CI * CB; i += stride) {      // w1 [256][64] -> w1t [64][256]
        int k = i / CB, n = i % CB;
        w1t[n * CI + k] = f2bf(w1[i]);
    }
    for (int i = tid; i < 9 * CB * CB; i += stride) {  // w2 [9][64][64] -> per-tap [n][k]
        int t = i / (CB * CB), rem = i % (CB * CB);
        int k = rem / CB, n = rem % CB;
        w2t[t * CB * CB + n * CB + k] = f2bf(w2[i]);
    }
    for (int i = tid; i < CB * CI; i += stride) {      // w3 [64][256] -> w3t [256][64]
        int k = i / CI, n = i % CI;
        w3t[n * CB + k] = f2bf(w3[i]);
    }
}

// ---------------- stage 1: out1 = relu((feats @ w1)*s1 + b1), N x 64 ----------------
// wave = 64 rows (4 m-tiles), full N=64 (4 n-tiles), K=256 (8 k-steps)

__global__ __launch_bounds__(256, 2) void k_gemm1(const float* __restrict__ feats,
                                                  const unsigned short* __restrict__ w1t,
                                                  const float* __restrict__ s1,
                                                  const float* __restrict__ b1,
                                                  unsigned short* __restrict__ out1) {
    const int wave = threadIdx.x >> 6;
    const int lane = threadIdx.x & 63;
    const int m = lane & 15;
    const int quad = lane >> 4;
    const int gw = blockIdx.x * 4 + wave;
    if (gw >= NN / 64) return;
    const int row0 = gw * 64;

    f32x4 acc[4][4];   // [mt][nt]
#pragma unroll
    for (int mt = 0; mt < 4; ++mt)
#pragma unroll
        for (int nt = 0; nt < 4; ++nt) acc[mt][nt] = (f32x4){0.f, 0.f, 0.f, 0.f};

#pragma unroll
    for (int ks = 0; ks < 8; ++ks) {
        bf16x8 a[4];
#pragma unroll
        for (int mt = 0; mt < 4; ++mt)
            a[mt] = ldfrag_f32(feats + (size_t)(row0 + mt * 16 + m) * CI + quad * 8 + ks * 32);
#pragma unroll
        for (int nt = 0; nt < 4; ++nt) {
            bf16x8 b = ldfrag(w1t + (nt * 16 + m) * CI + quad * 8 + ks * 32);
#pragma unroll
            for (int mt = 0; mt < 4; ++mt)
                acc[mt][nt] = mfma16(a[mt], b, acc[mt][nt]);
        }
    }

#pragma unroll
    for (int mt = 0; mt < 4; ++mt)
#pragma unroll
        for (int nt = 0; nt < 4; ++nt) {
            int col = nt * 16 + m;
            float sc = s1[col], bi = b1[col];
#pragma unroll
            for (int r = 0; r < 4; ++r) {
                int orow = row0 + mt * 16 + quad * 4 + r;
                float v = acc[mt][nt][r] * sc + bi;
                v = v > 0.f ? v : 0.f;
                out1[orow * CB + col] = f2bf(v);
            }
        }
}

// ---------------- stage 2: gathered 3x3 conv + bn2 + relu ----------------
// block = 256 rows; wave = 64 rows (4 m-tiles) x full N=64; nbr idx staged in LDS;
// branchless gather via zero-row pointer select.

__global__ __launch_bounds__(256, 2) void k_conv(const unsigned short* __restrict__ out1,
                                                 const unsigned short* __restrict__ w2t,
                                                 const int* __restrict__ coords,
                                                 const int* __restrict__ idx_map,
                                                 const float* __restrict__ s2,
                                                 const float* __restrict__ b2,
                                                 const unsigned short* __restrict__ zrow,
                                                 unsigned short* __restrict__ out2) {
    __shared__ int s_nbr[256 * 9];
    const int tid = threadIdx.x;
    const int grow = blockIdx.x * 256 + tid;
    if (grow < NN) {
        int c = coords[grow];
        int y = c / WW, x = c - y * WW;
#pragma unroll
        for (int t = 0; t < 9; ++t) {
            int dy = t / 3 - 1, dx = t % 3 - 1;
            int ny = y + dy, nx = x + dx;
            int r = -1;
            if (ny >= 0 && ny < HH && nx >= 0 && nx < WW) r = idx_map[ny * WW + nx];
            s_nbr[tid * 9 + t] = r;
        }
    } else {
#pragma unroll
        for (int t = 0; t < 9; ++t) s_nbr[tid * 9 + t] = -1;
    }
    __syncthreads();

    const int wave = tid >> 6;
    const int lane = tid & 63;
    const int m = lane & 15;
    const int quad = lane >> 4;
    const int row0 = blockIdx.x * 256 + wave * 64;
    if (row0 >= NN) return;

    f32x4 acc[4][4];   // [mt][nt]
#pragma unroll
    for (int mt = 0; mt < 4; ++mt)
#pragma unroll
        for (int nt = 0; nt < 4; ++nt) acc[mt][nt] = (f32x4){0.f, 0.f, 0.f, 0.f};

#pragma unroll
    for (int t = 0; t < 9; ++t) {
        bf16x8 a[4][2];
#pragma unroll
        for (int mt = 0; mt < 4; ++mt) {
            int r = s_nbr[(wave * 64 + mt * 16 + m) * 9 + t];
            const unsigned short* base = (r >= 0) ? (out1 + (size_t)r * CB) : zrow;
            a[mt][0] = ldfrag(base + quad * 8);
            a[mt][1] = ldfrag(base + quad * 8 + 32);
        }
#pragma unroll
        for (int ks = 0; ks < 2; ++ks)
#pragma unroll
            for (int nt = 0; nt < 4; ++nt) {
                bf16x8 b = ldfrag(w2t + t * CB * CB + (nt * 16 + m) * CB + quad * 8 + ks * 32);
#pragma unroll
                for (int mt = 0; mt < 4; ++mt)
                    acc[mt][nt] = mfma16(a[mt][ks], b, acc[mt][nt]);
            }
    }

#pragma unroll
    for (int mt = 0; mt < 4; ++mt)
#pragma unroll
        for (int nt = 0; nt < 4; ++nt) {
            int col = nt * 16 + m;
            float sc = s2[col], bi = b2[col];
#pragma unroll
            for (int r = 0; r < 4; ++r) {
                int orow = row0 + mt * 16 + quad * 4 + r;
                float v = acc[mt][nt][r] * sc + bi;
                v = v > 0.f ? v : 0.f;
                out2[orow * CB + col] = f2bf(v);
            }
        }
}

// ---------------- stage 3: out = relu((out2 @ w3)*s3 + b3 + feats), N x 256 ----------------
// block = 64 rows x 256 cols; wave = 64 rows x 64-col strip (4 m-tiles x 4 n-tiles), K=64

__global__ __launch_bounds__(256, 2) void k_gemm3(const unsigned short* __restrict__ out2,
                                                  const unsigned short* __restrict__ w3t,
                                                  const float* __restrict__ s3,
                                                  const float* __restrict__ b3,
                                                  const float* __restrict__ feats,
                                                  float* __restrict__ out) {
    const int wave = threadIdx.x >> 6;
    const int lane = threadIdx.x & 63;
    const int m = lane & 15;
    const int quad = lane >> 4;
    const int row0 = blockIdx.x * 64;
    const int col0 = wave * 64;

    f32x4 acc[4][4];   // [mt][nt]
#pragma unroll
    for (int mt = 0; mt < 4; ++mt)
#pragma unroll
        for (int nt = 0; nt < 4; ++nt) acc[mt][nt] = (f32x4){0.f, 0.f, 0.f, 0.f};

    bf16x8 a[4][2];
#pragma unroll
    for (int mt = 0; mt < 4; ++mt) {
        const unsigned short* ap = out2 + (size_t)(row0 + mt * 16 + m) * CB + quad * 8;
        a[mt][0] = ldfrag(ap);
        a[mt][1] = ldfrag(ap + 32);
    }
#pragma unroll
    for (int ks = 0; ks < 2; ++ks)
#pragma unroll
        for (int nt = 0; nt < 4; ++nt) {
            bf16x8 b = ldfrag(w3t + (col0 + nt * 16 + m) * CB + quad * 8 + ks * 32);
#pragma unroll
            for (int mt = 0; mt < 4; ++mt)
                acc[mt][nt] = mfma16(a[mt][ks], b, acc[mt][nt]);
        }

#pragma unroll
    for (int mt = 0; mt < 4; ++mt)
#pragma unroll
        for (int nt = 0; nt < 4; ++nt) {
            int col = col0 + nt * 16 + m;
            float sc = s3[col], bi = b3[col];
#pragma unroll
            for (int r = 0; r < 4; ++r) {
                int orow = row0 + mt * 16 + quad * 4 + r;
                float v = acc[mt][nt][r] * sc + bi + feats[(size_t)orow * CI + col];
                v = v > 0.f ? v : 0.f;
                out[(size_t)orow * CI + col] = v;
            }
        }
}

// ---------------- launch ----------------

extern "C" void kernel_launch(void* const* d_in, const int* in_sizes, int n_in,
                              void* d_out, int out_size, void* d_ws, size_t ws_size,
                              hipStream_t stream) {
    const float* feats = (const float*)d_in[0];
    const int* coords = (const int*)d_in[1];
    const float* w1 = (const float*)d_in[2];
    const float* w2 = (const float*)d_in[3];
    const float* w3 = (const float*)d_in[4];
    const float* s1 = (const float*)d_in[5];
    const float* b1 = (const float*)d_in[6];
    const float* s2 = (const float*)d_in[7];
    const float* b2 = (const float*)d_in[8];
    const float* s3 = (const float*)d_in[9];
    const float* b3 = (const float*)d_in[10];
    float* out = (float*)d_out;

    char* ws = (char*)d_ws;
    int* idx_map        = (int*)(ws + 0);                       // 2,359,296
    unsigned short* w1t = (unsigned short*)(ws + 2359296);      // 32,768
    unsigned short* w2t = (unsigned short*)(ws + 2392064);      // 73,728
    unsigned short* w3t = (unsigned short*)(ws + 2465792);      // 32,768
    unsigned short* out1= (unsigned short*)(ws + 2498560);      // 25,600,000
    unsigned short* out2= (unsigned short*)(ws + 28098560);     // 25,600,000
    unsigned short* zrow= (unsigned short*)(ws + 53698560);     // 128 zero bytes
    // total: 53,698,688 bytes

    hipMemsetAsync(idx_map, 0xFF, (size_t)HH * WW * 4, stream);
    hipMemsetAsync(zrow, 0x00, 128, stream);
    k_scatter<<<(NN + 255) / 256, 256, 0, stream>>>(coords, idx_map);
    k_prepw<<<64, 256, 0, stream>>>(w1, w2, w3, w1t, w2t, w3t);
    k_gemm1<<<(NN / 64 + 3) / 4, 256, 0, stream>>>(feats, w1t, s1, b1, out1);
    k_conv<<<(NN + 255) / 256, 256, 0, stream>>>(out1, w2t, coords, idx_map, s2, b2, zrow, out2);
    k_gemm3<<<NN / 64, 256, 0, stream>>>(out2, w3t, s3, b3, feats, out);
}